// Round 1
// baseline (236.519 us; speedup 1.0000x reference)
//
#include <hip/hip_runtime.h>
#include <hip/hip_bf16.h>
#include <math.h>

// Problem constants: B=16, C=OUP=64, H=W=128, HW=16384, M=10
#define NB   16
#define NC   64
#define NH   128
#define NW   128
#define NHW  16384
#define NM   10

// ---------------------------------------------------------------------------
// K0: g[b,c] = mean over HW of x[b,c,:,:]   (f64 accumulation)
// ---------------------------------------------------------------------------
__global__ __launch_bounds__(256) void k_gmean(const float* __restrict__ x,
                                               double* __restrict__ g) {
    int bc = blockIdx.x;                     // 0..1023
    const float* xp = x + (size_t)bc * NHW;
    double s = 0.0;
    for (int i = threadIdx.x; i < NHW; i += 256) s += (double)xp[i];
    for (int off = 32; off; off >>= 1) s += __shfl_down(s, off);
    __shared__ double red[4];
    int wid = threadIdx.x >> 6, lane = threadIdx.x & 63;
    if (lane == 0) red[wid] = s;
    __syncthreads();
    if (threadIdx.x == 0)
        g[bc] = (red[0] + red[1] + red[2] + red[3]) * (1.0 / (double)NHW);
}

// ---------------------------------------------------------------------------
// K1: x_c = 1x1 conv (W[64,64] @ x) fused with cosine-sim S (f64)
// one thread per pixel (b,k); 64 channels live in registers
// ---------------------------------------------------------------------------
__global__ __launch_bounds__(256) void k_conv1_S(
        const float* __restrict__ x, const float* __restrict__ W,
        const double* __restrict__ g, float* __restrict__ xc,
        double* __restrict__ S) {
    int P = blockIdx.x * 256 + threadIdx.x;  // global pixel id
    int b = P >> 14, k = P & (NHW - 1);
    const float* xb = x + (size_t)b * NC * NHW + k;
    const double* gb = g + b * NC;

    float xv[NC];
    double num = 0.0, sq = 0.0, gsq = 0.0;
#pragma unroll
    for (int c = 0; c < NC; ++c) {
        float v = xb[(size_t)c * NHW];
        xv[c] = v;
        double gc = gb[c];
        num += gc * (double)v;
        sq  += (double)v * (double)v;
        gsq += gc * gc;
    }
    double gn = fmax(sqrt(gsq), 1e-8);
    double xn = fmax(sqrt(sq), 1e-8);
    S[P] = num / (gn * xn);

    float* xcb = xc + (size_t)b * NC * NHW + k;
#pragma unroll
    for (int o = 0; o < NC; ++o) {
        float acc = 0.f;
        const float* wr = W + o * NC;        // wave-uniform -> scalar loads
#pragma unroll
        for (int c = 0; c < NC; ++c) acc = fmaf(wr[c], xv[c], acc);
        xcb[(size_t)o * NHW] = acc;
    }
}

// ---------------------------------------------------------------------------
// K2: fused depthwise chain (bn0,c1h,bn1,c2v,bn2,c3h-dil2,bn3,c4v-dil2,bn4)
// block = (tile 32x32, channel, batch); writes x_center into d_out (scratch)
// ---------------------------------------------------------------------------
__global__ __launch_bounds__(256) void k_dwchain(
        const float* __restrict__ xc,
        const float* __restrict__ pw1, const float* __restrict__ pw2,
        const float* __restrict__ pw3, const float* __restrict__ pw4,
        const float* __restrict__ gamma, const float* __restrict__ beta,
        float* __restrict__ outp) {
    int tile = blockIdx.x, c = blockIdx.y, b = blockIdx.z;
    int ty0 = (tile >> 2) * 32, tx0 = (tile & 3) * 32;
    const float inv = 0.9999950000374997f;   // 1/sqrt(1+1e-5)
    float s0 = gamma[0*NC+c]*inv, b0 = beta[0*NC+c];
    float s1 = gamma[1*NC+c]*inv, b1 = beta[1*NC+c];
    float s2 = gamma[2*NC+c]*inv, b2 = beta[2*NC+c];
    float s3 = gamma[3*NC+c]*inv, b3 = beta[3*NC+c];
    float s4 = gamma[4*NC+c]*inv, b4 = beta[4*NC+c];
    float w1[5], w2[5], w3[5], w4[5];
#pragma unroll
    for (int q = 0; q < 5; ++q) {
        w1[q] = pw1[c*5+q]; w2[q] = pw2[c*5+q];
        w3[q] = pw3[c*5+q]; w4[q] = pw4[c*5+q];
    }
    __shared__ float A[44*44];
    __shared__ float Bf[44*40];
    const float* src = xc + ((size_t)(b*NC + c)) * NHW;

    // h0 = bn0(x_c), 44x44 halo tile, zero outside image (conv zero-padding)
    for (int e = threadIdx.x; e < 44*44; e += 256) {
        int r = e / 44, cc = e - r*44;
        int gy = ty0 - 6 + r, gx = tx0 - 6 + cc;
        float v = 0.f;
        if (gy >= 0 && gy < NH && gx >= 0 && gx < NW)
            v = src[gy*NW + gx] * s0 + b0;
        A[e] = v;
    }
    __syncthreads();
    // stage1: horizontal 1x5 + bn1 -> Bf[44][40]
    for (int e = threadIdx.x; e < 44*40; e += 256) {
        int r = e / 40, cp = e - r*40;
        int gy = ty0 - 6 + r, gx = tx0 - 4 + cp;
        float v = 0.f;
        if (gy >= 0 && gy < NH && gx >= 0 && gx < NW) {
            float acc = 0.f;
#pragma unroll
            for (int q = 0; q < 5; ++q) acc = fmaf(w1[q], A[r*44 + cp + q], acc);
            v = acc * s1 + b1;
        }
        Bf[e] = v;
    }
    __syncthreads();
    // stage2: vertical 5x1 + bn2 -> A[40][40]
    for (int e = threadIdx.x; e < 40*40; e += 256) {
        int r = e / 40, cp = e - r*40;
        int gy = ty0 - 4 + r, gx = tx0 - 4 + cp;
        float v = 0.f;
        if (gy >= 0 && gy < NH && gx >= 0 && gx < NW) {
            float acc = 0.f;
#pragma unroll
            for (int p = 0; p < 5; ++p) acc = fmaf(w2[p], Bf[(r+p)*40 + cp], acc);
            v = acc * s2 + b2;
        }
        A[e] = v;
    }
    __syncthreads();
    // stage3: horizontal 1x5 dil2 + bn3 -> Bf[40][32]
    for (int e = threadIdx.x; e < 40*32; e += 256) {
        int r = e / 32, c3 = e - r*32;
        int gy = ty0 - 4 + r;
        float v = 0.f;
        if (gy >= 0 && gy < NH) {
            float acc = 0.f;
#pragma unroll
            for (int q = 0; q < 5; ++q) acc = fmaf(w3[q], A[r*40 + c3 + 2*q], acc);
            v = acc * s3 + b3;
        }
        Bf[e] = v;
    }
    __syncthreads();
    // stage4: vertical 5x1 dil2 + bn4 -> x_center (d_out scratch)
    float* dst = outp + ((size_t)(b*NC + c)) * NHW;
    for (int e = threadIdx.x; e < 32*32; e += 256) {
        int r = e / 32, c3 = e - r*32;
        float acc = 0.f;
#pragma unroll
        for (int p = 0; p < 5; ++p) acc = fmaf(w4[p], Bf[(r+2*p)*32 + c3], acc);
        dst[(ty0+r)*NW + tx0 + c3] = acc * s4 + b4;
    }
}

// ---------------------------------------------------------------------------
// K3: per-batch chain: min/max -> levels -> histogram -> Ch -> Cf(=Cq view)
//     -> p1,p2,p3 -> softmax attention X -> Lp.   One block per batch.
// ---------------------------------------------------------------------------
__global__ __launch_bounds__(256) void k_chain(
        const double* __restrict__ S,
        const float* __restrict__ fc1w, const float* __restrict__ fc1b,
        const float* __restrict__ ph1w, const float* __restrict__ ph1b,
        const float* __restrict__ ph2w, const float* __restrict__ ph2b,
        const float* __restrict__ ph3w, const float* __restrict__ ph3b,
        double* __restrict__ levelsOut, float* __restrict__ LpOut) {
    int b = blockIdx.x, tid = threadIdx.x;
    const double* Sb = S + b * NHW;

    // --- min/max (exact, order independent) ---
    double mn = 1e300, mx = -1e300;
    for (int i = tid; i < NHW; i += 256) {
        double v = Sb[i];
        mn = fmin(mn, v); mx = fmax(mx, v);
    }
    for (int off = 32; off; off >>= 1) {
        mn = fmin(mn, __shfl_down(mn, off));
        mx = fmax(mx, __shfl_down(mx, off));
    }
    __shared__ double rmn[4], rmx[4];
    int wid = tid >> 6, lane = tid & 63;
    if (lane == 0) { rmn[wid] = mn; rmx[wid] = mx; }
    __syncthreads();
    __shared__ double levS[NM];
    if (tid == 0) {
        double a = fmin(fmin(rmn[0], rmn[1]), fmin(rmn[2], rmn[3]));
        double z = fmax(fmax(rmx[0], rmx[1]), fmax(rmx[2], rmx[3]));
        for (int m = 0; m < NM; ++m) levS[m] = a + (z - a) * ((double)m / 9.0);
    }
    __syncthreads();
    double lv[NM];
#pragma unroll
    for (int m = 0; m < NM; ++m) lv[m] = levS[m];

    // --- histogram colsum (f64) ---
    double bins[NM];
#pragma unroll
    for (int m = 0; m < NM; ++m) bins[m] = 0.0;
    for (int i = tid; i < NHW; i += 256) {
        double v = Sb[i];
#pragma unroll
        for (int m = 0; m < NM; ++m) {
            double d = fabs(lv[m] - v);
            if (d < 0.05) bins[m] += 1.0 - d;
        }
    }
#pragma unroll
    for (int m = 0; m < NM; ++m)
        for (int off = 32; off; off >>= 1) bins[m] += __shfl_down(bins[m], off);
    __shared__ double wb[4][NM];
    if (lane == 0) {
#pragma unroll
        for (int m = 0; m < NM; ++m) wb[wid][m] = bins[m];
    }
    __syncthreads();
    __shared__ float ratio[NM];
    if (tid == 0) {
        double den = 0.0;
        for (int m = 0; m < NM; ++m) {
            double cs = wb[0][m] + wb[1][m] + wb[2][m] + wb[3][m];
            den += cs;
            ratio[m] = (float)(cs / den);   // colsum / cumsum
        }
    }
    __syncthreads();

    // --- Cf [10 rows][64]; flat CfL[r*64+o]; Cq[c][m] == CfL[c*10+m] ---
    __shared__ float CfL[640];
    for (int idx = tid; idx < 640; idx += 256) {
        int rm = idx >> 6, o = idx & 63;
        CfL[idx] = ratio[rm] * fc1w[o*2+0] + (float)levS[rm] * fc1w[o*2+1] + fc1b[o];
    }
    __syncthreads();

    // --- p1,p2,p3 [64][10] ---
    __shared__ float P1[640], P2[640], P3[640];
    for (int idx = tid; idx < 640; idx += 256) {
        int o = idx / 10, m = idx - o * 10;
        float a1 = ph1b[o], a2 = ph2b[o], a3 = ph3b[o];
        for (int c2 = 0; c2 < NC; ++c2) {
            float cq = CfL[c2*10 + m];
            a1 = fmaf(ph1w[o*NC + c2], cq, a1);
            a2 = fmaf(ph2w[o*NC + c2], cq, a2);
            a3 = fmaf(ph3w[o*NC + c2], cq, a3);
        }
        P1[idx] = a1; P2[idx] = a2; P3[idx] = a3;
    }
    __syncthreads();

    // --- A[m][n] = sum_c p1[c,m] p2[c,n]; softmax over n ---
    __shared__ float XL[100];
    if (tid < 100) {
        int m = tid / 10, n = tid - (tid/10)*10;
        float acc = 0.f;
        for (int c2 = 0; c2 < NC; ++c2)
            acc = fmaf(P1[c2*10 + m], P2[c2*10 + n], acc);
        XL[tid] = acc;
    }
    __syncthreads();
    if (tid < NM) {
        float mxr = XL[tid*10];
        for (int n = 1; n < NM; ++n) mxr = fmaxf(mxr, XL[tid*10 + n]);
        float e[NM], sum = 0.f;
        for (int n = 0; n < NM; ++n) { e[n] = expf(XL[tid*10+n] - mxr); sum += e[n]; }
        for (int n = 0; n < NM; ++n) XL[tid*10+n] = e[n] / sum;
    }
    __syncthreads();

    // --- Lp[c][n] = sum_m p3[c,m] X[m,n] ---
    for (int idx = tid; idx < 640; idx += 256) {
        int c2 = idx / 10, n = idx - (idx/10)*10;
        float acc = 0.f;
#pragma unroll
        for (int m = 0; m < NM; ++m) acc = fmaf(P3[c2*10 + m], XL[m*10 + n], acc);
        LpOut[b*640 + idx] = acc;
    }
    if (tid < NM) levelsOut[b*NM + tid] = levS[tid];
}

// ---------------------------------------------------------------------------
// K4: final fusion. Per pixel: v[10] from scattered S (Vr raw-reshape trick),
// then per channel: R = Lp·v, att = sigmoid(x_full + x_tex + x_center),
// out = x*att. x_center is read from d_out (read-before-write, 1:1 mapping).
// ---------------------------------------------------------------------------
__global__ __launch_bounds__(256) void k_final(
        const float* __restrict__ x, const double* __restrict__ S,
        const double* __restrict__ levels, const float* __restrict__ Lp,
        const float* __restrict__ bn1g, const float* __restrict__ bn1b,
        const float* __restrict__ bn2g, const float* __restrict__ bn2b,
        const float* __restrict__ wconv2, float* out) {
    int P = blockIdx.x * 256 + threadIdx.x;
    int b = P >> 14, k = P & (NHW - 1);

    __shared__ float  LpL[640], Ac[NC], Bc[NC], S1[NC];
    __shared__ double levL[NM];
    const float inv = 0.9999950000374997f;
    for (int e = threadIdx.x; e < 640; e += 256) LpL[e] = Lp[b*640 + e];
    if (threadIdx.x < NM) levL[threadIdx.x] = levels[b*NM + threadIdx.x];
    if (threadIdx.x < NC) {
        int c = threadIdx.x;
        Ac[c] = wconv2[c] * (bn2g[c] * inv);       // scales S
        Bc[c] = bn2b[c] + bn1b[c];                 // combined shifts
        S1[c] = bn1g[c] * inv;                     // scales R
    }
    __syncthreads();

    const double* Sb = S + (size_t)b * NHW;
    float v[NM];
#pragma unroll
    for (int i = 0; i < NM; ++i) {
        int j = i * NHW + k;
        int p = j / 10;
        int m = j - p * 10;
        double d = fabs(levL[m] - Sb[p]);
        v[i] = (d < 0.05) ? (float)(1.0 - d) : 0.f;
    }
    float Sk = (float)Sb[k];

    size_t base = (size_t)b * NC * NHW + k;
#pragma unroll 4
    for (int c = 0; c < NC; ++c) {
        float R = 0.f;
#pragma unroll
        for (int i = 0; i < NM; ++i) R = fmaf(LpL[c*10 + i], v[i], R);
        float xcen = out[base + (size_t)c * NHW];      // x_center scratch
        float pre = fmaf(Ac[c], Sk, Bc[c]) + S1[c] * R + xcen;
        float att = 1.0f / (1.0f + expf(-pre));
        out[base + (size_t)c * NHW] = x[base + (size_t)c * NHW] * att;
    }
}

// ---------------------------------------------------------------------------
extern "C" void kernel_launch(void* const* d_in, const int* in_sizes, int n_in,
                              void* d_out, int out_size, void* d_ws, size_t ws_size,
                              hipStream_t stream) {
    (void)in_sizes; (void)n_in; (void)out_size; (void)ws_size;
    const float* x      = (const float*)d_in[0];
    const float* wconv1 = (const float*)d_in[1];
    const float* pw1    = (const float*)d_in[2];
    const float* pw2    = (const float*)d_in[3];
    const float* pw3    = (const float*)d_in[4];
    const float* pw4    = (const float*)d_in[5];
    const float* pgam   = (const float*)d_in[6];
    const float* pbet   = (const float*)d_in[7];
    const float* bn1g   = (const float*)d_in[8];
    const float* bn1b   = (const float*)d_in[9];
    const float* bn2g   = (const float*)d_in[10];
    const float* bn2b   = (const float*)d_in[11];
    const float* fc1w   = (const float*)d_in[12];
    const float* fc1b   = (const float*)d_in[13];
    const float* ph1w   = (const float*)d_in[14];
    const float* ph1b   = (const float*)d_in[15];
    const float* ph2w   = (const float*)d_in[16];
    const float* ph2b   = (const float*)d_in[17];
    const float* ph3w   = (const float*)d_in[18];
    const float* ph3b   = (const float*)d_in[19];
    const float* wconv2 = (const float*)d_in[20];
    float* out = (float*)d_out;

    // workspace layout
    float*  ws  = (float*)d_ws;
    float*  xc  = ws;                                   // 16777216 f32
    double* Sd  = (double*)(ws + 16777216);             // 262144 f64
    double* g   = Sd + NB * NHW;                        // 1024 f64
    double* lev = g + NB * NC;                          // 160 f64
    float*  Lp  = (float*)(lev + NB * NM);              // 10240 f32
    // total ~69.3 MB

    k_gmean<<<NB * NC, 256, 0, stream>>>(x, g);
    k_conv1_S<<<NB * NHW / 256, 256, 0, stream>>>(x, wconv1, g, xc, Sd);
    k_dwchain<<<dim3(16, NC, NB), 256, 0, stream>>>(xc, pw1, pw2, pw3, pw4,
                                                    pgam, pbet, out);
    k_chain<<<NB, 256, 0, stream>>>(Sd, fc1w, fc1b, ph1w, ph1b, ph2w, ph2b,
                                    ph3w, ph3b, lev, Lp);
    k_final<<<NB * NHW / 256, 256, 0, stream>>>(x, Sd, lev, Lp,
                                                bn1g, bn1b, bn2g, bn2b,
                                                wconv2, out);
}

// Round 2
// 213.294 us; speedup vs baseline: 1.1089x; 1.1089x over previous
//
#include <hip/hip_runtime.h>
#include <hip/hip_bf16.h>
#include <math.h>

// Problem constants: B=16, C=OUP=64, H=W=128, HW=16384, M=10
#define NB   16
#define NC   64
#define NH   128
#define NW   128
#define NHW  16384
#define NM   10

// ---------------------------------------------------------------------------
// K0: g[b,c] = mean over HW of x[b,c,:,:]   (f64 accumulation, float4 loads)
// ---------------------------------------------------------------------------
__global__ __launch_bounds__(256) void k_gmean(const float* __restrict__ x,
                                               double* __restrict__ g) {
    int bc = blockIdx.x;                     // 0..1023
    const float* xp = x + (size_t)bc * NHW;
    double s = 0.0;
    for (int i = threadIdx.x; i < NHW / 4; i += 256) {
        float4 v = ((const float4*)xp)[i];
        s += (double)v.x + (double)v.y + (double)v.z + (double)v.w;
    }
    for (int off = 32; off; off >>= 1) s += __shfl_down(s, off);
    __shared__ double red[4];
    int wid = threadIdx.x >> 6, lane = threadIdx.x & 63;
    if (lane == 0) red[wid] = s;
    __syncthreads();
    if (threadIdx.x == 0)
        g[bc] = (red[0] + red[1] + red[2] + red[3]) * (1.0 / (double)NHW);
}

// ---------------------------------------------------------------------------
// K1: x_c = 1x1 conv (W[64,64] @ x) fused with cosine-sim S (f64)
// LDS-tiled GEMM: block = 256-pixel tile; X[64c][256px] + Wt[64c][64o] in LDS;
// each thread computes an 8o x 8px register tile.
// ---------------------------------------------------------------------------
__global__ __launch_bounds__(256) void k_conv1_S(
        const float* __restrict__ x, const float* __restrict__ W,
        const double* __restrict__ g, float* __restrict__ xc,
        double* __restrict__ S) {
    __shared__ float Xs[64 * 256];           // 64 KB, row stride 1024B
    __shared__ float Wt[64 * 64];            // 16 KB, Wt[c][o] = W[o][c]
    int bid = blockIdx.x;
    int b = bid >> 6, k0 = (bid & 63) * 256; // 64 tiles per batch
    int tid = threadIdx.x;
    const float* xb = x + (size_t)b * NC * NHW + k0;

    // stage W transposed (16 KB, L2-resident after first block)
    for (int e = tid; e < 64 * 64; e += 256) {
        int c = e >> 6, o = e & 63;
        Wt[c * 64 + o] = W[o * 64 + c];
    }
    // stage X tile, float4 coalesced
    for (int e = tid; e < 64 * 64; e += 256) {
        int c = e >> 6, p4 = (e & 63) << 2;
        *(float4*)&Xs[c * 256 + p4] =
            *(const float4*)&xb[(size_t)c * NHW + p4];
    }
    __syncthreads();

    // ---- S phase: one pixel per thread, f64 (same arithmetic as before) ----
    {
        const double* gb = g + b * NC;
        double num = 0.0, sq = 0.0, gsq = 0.0;
#pragma unroll
        for (int c = 0; c < NC; ++c) {
            double v = (double)Xs[c * 256 + tid];
            double gc = gb[c];
            num += gc * v;
            sq  += v * v;
            gsq += gc * gc;
        }
        double gn = fmax(sqrt(gsq), 1e-8);
        double xn = fmax(sqrt(sq), 1e-8);
        S[(size_t)b * NHW + k0 + tid] = num / (gn * xn);
    }

    // ---- GEMM phase: thread (og,pg) -> o0=og*8, px0=pg*8 ----
    int pg = tid & 31, og = tid >> 5;
    int px0 = pg * 8, o0 = og * 8;
    float acc[8][8];
#pragma unroll
    for (int i = 0; i < 8; ++i)
#pragma unroll
        for (int j = 0; j < 8; ++j) acc[i][j] = 0.f;

#pragma unroll 4
    for (int c = 0; c < NC; ++c) {
        float4 xa = *(float4*)&Xs[c * 256 + px0];
        float4 xb2 = *(float4*)&Xs[c * 256 + px0 + 4];
        float4 wa = *(float4*)&Wt[c * 64 + o0];
        float4 wb2 = *(float4*)&Wt[c * 64 + o0 + 4];
        float xr[8] = {xa.x, xa.y, xa.z, xa.w, xb2.x, xb2.y, xb2.z, xb2.w};
        float wr[8] = {wa.x, wa.y, wa.z, wa.w, wb2.x, wb2.y, wb2.z, wb2.w};
#pragma unroll
        for (int i = 0; i < 8; ++i)
#pragma unroll
            for (int j = 0; j < 8; ++j)
                acc[i][j] = fmaf(wr[i], xr[j], acc[i][j]);
    }

    float* xcb = xc + (size_t)b * NC * NHW + k0;
#pragma unroll
    for (int i = 0; i < 8; ++i) {
        float4 s0, s1;
        s0.x = acc[i][0]; s0.y = acc[i][1]; s0.z = acc[i][2]; s0.w = acc[i][3];
        s1.x = acc[i][4]; s1.y = acc[i][5]; s1.z = acc[i][6]; s1.w = acc[i][7];
        *(float4*)&xcb[(size_t)(o0 + i) * NHW + px0] = s0;
        *(float4*)&xcb[(size_t)(o0 + i) * NHW + px0 + 4] = s1;
    }
}

// ---------------------------------------------------------------------------
// K2: fused depthwise chain (bn0,c1h,bn1,c2v,bn2,c3h-dil2,bn3,c4v-dil2,bn4)
// block = (tile 32x32, channel, batch); writes x_center into d_out (scratch)
// ---------------------------------------------------------------------------
__global__ __launch_bounds__(256) void k_dwchain(
        const float* __restrict__ xc,
        const float* __restrict__ pw1, const float* __restrict__ pw2,
        const float* __restrict__ pw3, const float* __restrict__ pw4,
        const float* __restrict__ gamma, const float* __restrict__ beta,
        float* __restrict__ outp) {
    int tile = blockIdx.x, c = blockIdx.y, b = blockIdx.z;
    int ty0 = (tile >> 2) * 32, tx0 = (tile & 3) * 32;
    const float inv = 0.9999950000374997f;   // 1/sqrt(1+1e-5)
    float s0 = gamma[0*NC+c]*inv, b0 = beta[0*NC+c];
    float s1 = gamma[1*NC+c]*inv, b1 = beta[1*NC+c];
    float s2 = gamma[2*NC+c]*inv, b2 = beta[2*NC+c];
    float s3 = gamma[3*NC+c]*inv, b3 = beta[3*NC+c];
    float s4 = gamma[4*NC+c]*inv, b4 = beta[4*NC+c];
    float w1[5], w2[5], w3[5], w4[5];
#pragma unroll
    for (int q = 0; q < 5; ++q) {
        w1[q] = pw1[c*5+q]; w2[q] = pw2[c*5+q];
        w3[q] = pw3[c*5+q]; w4[q] = pw4[c*5+q];
    }
    __shared__ float A[44*44];
    __shared__ float Bf[44*40];
    const float* src = xc + ((size_t)(b*NC + c)) * NHW;

    // h0 = bn0(x_c), 44x44 halo tile, zero outside image (conv zero-padding)
    for (int e = threadIdx.x; e < 44*44; e += 256) {
        int r = e / 44, cc = e - r*44;
        int gy = ty0 - 6 + r, gx = tx0 - 6 + cc;
        float v = 0.f;
        if (gy >= 0 && gy < NH && gx >= 0 && gx < NW)
            v = src[gy*NW + gx] * s0 + b0;
        A[e] = v;
    }
    __syncthreads();
    // stage1: horizontal 1x5 + bn1 -> Bf[44][40]
    for (int e = threadIdx.x; e < 44*40; e += 256) {
        int r = e / 40, cp = e - r*40;
        int gy = ty0 - 6 + r, gx = tx0 - 4 + cp;
        float v = 0.f;
        if (gy >= 0 && gy < NH && gx >= 0 && gx < NW) {
            float acc = 0.f;
#pragma unroll
            for (int q = 0; q < 5; ++q) acc = fmaf(w1[q], A[r*44 + cp + q], acc);
            v = acc * s1 + b1;
        }
        Bf[e] = v;
    }
    __syncthreads();
    // stage2: vertical 5x1 + bn2 -> A[40][40]
    for (int e = threadIdx.x; e < 40*40; e += 256) {
        int r = e / 40, cp = e - r*40;
        int gy = ty0 - 4 + r, gx = tx0 - 4 + cp;
        float v = 0.f;
        if (gy >= 0 && gy < NH && gx >= 0 && gx < NW) {
            float acc = 0.f;
#pragma unroll
            for (int p = 0; p < 5; ++p) acc = fmaf(w2[p], Bf[(r+p)*40 + cp], acc);
            v = acc * s2 + b2;
        }
        A[e] = v;
    }
    __syncthreads();
    // stage3: horizontal 1x5 dil2 + bn3 -> Bf[40][32]
    for (int e = threadIdx.x; e < 40*32; e += 256) {
        int r = e / 32, c3 = e - r*32;
        int gy = ty0 - 4 + r;
        float v = 0.f;
        if (gy >= 0 && gy < NH) {
            float acc = 0.f;
#pragma unroll
            for (int q = 0; q < 5; ++q) acc = fmaf(w3[q], A[r*40 + c3 + 2*q], acc);
            v = acc * s3 + b3;
        }
        Bf[e] = v;
    }
    __syncthreads();
    // stage4: vertical 5x1 dil2 + bn4 -> x_center (d_out scratch)
    float* dst = outp + ((size_t)(b*NC + c)) * NHW;
    for (int e = threadIdx.x; e < 32*32; e += 256) {
        int r = e / 32, c3 = e - r*32;
        float acc = 0.f;
#pragma unroll
        for (int p = 0; p < 5; ++p) acc = fmaf(w4[p], Bf[(r+2*p)*32 + c3], acc);
        dst[(ty0+r)*NW + tx0 + c3] = acc * s4 + b4;
    }
}

// ---------------------------------------------------------------------------
// K3: per-batch chain: min/max -> levels -> histogram -> Ch -> Cf(=Cq view)
//     -> p1,p2,p3 -> softmax attention X -> Lp.   One block per batch.
// ---------------------------------------------------------------------------
__global__ __launch_bounds__(256) void k_chain(
        const double* __restrict__ S,
        const float* __restrict__ fc1w, const float* __restrict__ fc1b,
        const float* __restrict__ ph1w, const float* __restrict__ ph1b,
        const float* __restrict__ ph2w, const float* __restrict__ ph2b,
        const float* __restrict__ ph3w, const float* __restrict__ ph3b,
        double* __restrict__ levelsOut, float* __restrict__ LpOut) {
    int b = blockIdx.x, tid = threadIdx.x;
    const double* Sb = S + b * NHW;

    // --- min/max (exact, order independent) ---
    double mn = 1e300, mx = -1e300;
    for (int i = tid; i < NHW; i += 256) {
        double v = Sb[i];
        mn = fmin(mn, v); mx = fmax(mx, v);
    }
    for (int off = 32; off; off >>= 1) {
        mn = fmin(mn, __shfl_down(mn, off));
        mx = fmax(mx, __shfl_down(mx, off));
    }
    __shared__ double rmn[4], rmx[4];
    int wid = tid >> 6, lane = tid & 63;
    if (lane == 0) { rmn[wid] = mn; rmx[wid] = mx; }
    __syncthreads();
    __shared__ double levS[NM];
    if (tid == 0) {
        double a = fmin(fmin(rmn[0], rmn[1]), fmin(rmn[2], rmn[3]));
        double z = fmax(fmax(rmx[0], rmx[1]), fmax(rmx[2], rmx[3]));
        for (int m = 0; m < NM; ++m) levS[m] = a + (z - a) * ((double)m / 9.0);
    }
    __syncthreads();
    double lv[NM];
#pragma unroll
    for (int m = 0; m < NM; ++m) lv[m] = levS[m];

    // --- histogram colsum (f64) ---
    double bins[NM];
#pragma unroll
    for (int m = 0; m < NM; ++m) bins[m] = 0.0;
    for (int i = tid; i < NHW; i += 256) {
        double v = Sb[i];
#pragma unroll
        for (int m = 0; m < NM; ++m) {
            double d = fabs(lv[m] - v);
            if (d < 0.05) bins[m] += 1.0 - d;
        }
    }
#pragma unroll
    for (int m = 0; m < NM; ++m)
        for (int off = 32; off; off >>= 1) bins[m] += __shfl_down(bins[m], off);
    __shared__ double wb[4][NM];
    if (lane == 0) {
#pragma unroll
        for (int m = 0; m < NM; ++m) wb[wid][m] = bins[m];
    }
    __syncthreads();
    __shared__ float ratio[NM];
    if (tid == 0) {
        double den = 0.0;
        for (int m = 0; m < NM; ++m) {
            double cs = wb[0][m] + wb[1][m] + wb[2][m] + wb[3][m];
            den += cs;
            ratio[m] = (float)(cs / den);   // colsum / cumsum
        }
    }
    __syncthreads();

    // --- Cf [10 rows][64]; flat CfL[r*64+o]; Cq[c][m] == CfL[c*10+m] ---
    __shared__ float CfL[640];
    for (int idx = tid; idx < 640; idx += 256) {
        int rm = idx >> 6, o = idx & 63;
        CfL[idx] = ratio[rm] * fc1w[o*2+0] + (float)levS[rm] * fc1w[o*2+1] + fc1b[o];
    }
    __syncthreads();

    // --- p1,p2,p3 [64][10] ---
    __shared__ float P1[640], P2[640], P3[640];
    for (int idx = tid; idx < 640; idx += 256) {
        int o = idx / 10, m = idx - o * 10;
        float a1 = ph1b[o], a2 = ph2b[o], a3 = ph3b[o];
        for (int c2 = 0; c2 < NC; ++c2) {
            float cq = CfL[c2*10 + m];
            a1 = fmaf(ph1w[o*NC + c2], cq, a1);
            a2 = fmaf(ph2w[o*NC + c2], cq, a2);
            a3 = fmaf(ph3w[o*NC + c2], cq, a3);
        }
        P1[idx] = a1; P2[idx] = a2; P3[idx] = a3;
    }
    __syncthreads();

    // --- A[m][n] = sum_c p1[c,m] p2[c,n]; softmax over n ---
    __shared__ float XL[100];
    if (tid < 100) {
        int m = tid / 10, n = tid - (tid/10)*10;
        float acc = 0.f;
        for (int c2 = 0; c2 < NC; ++c2)
            acc = fmaf(P1[c2*10 + m], P2[c2*10 + n], acc);
        XL[tid] = acc;
    }
    __syncthreads();
    if (tid < NM) {
        float mxr = XL[tid*10];
        for (int n = 1; n < NM; ++n) mxr = fmaxf(mxr, XL[tid*10 + n]);
        float e[NM], sum = 0.f;
        for (int n = 0; n < NM; ++n) { e[n] = expf(XL[tid*10+n] - mxr); sum += e[n]; }
        for (int n = 0; n < NM; ++n) XL[tid*10+n] = e[n] / sum;
    }
    __syncthreads();

    // --- Lp[c][n] = sum_m p3[c,m] X[m,n] ---
    for (int idx = tid; idx < 640; idx += 256) {
        int c2 = idx / 10, n = idx - (idx/10)*10;
        float acc = 0.f;
#pragma unroll
        for (int m = 0; m < NM; ++m) acc = fmaf(P3[c2*10 + m], XL[m*10 + n], acc);
        LpOut[b*640 + idx] = acc;
    }
    if (tid < NM) levelsOut[b*NM + tid] = levS[tid];
}

// ---------------------------------------------------------------------------
// K4: final fusion. Per pixel: v[10] from scattered S (Vr raw-reshape trick),
// then per channel: R = Lp·v, att = sigmoid(x_full + x_tex + x_center),
// out = x*att. x_center is read from d_out (read-before-write, 1:1 mapping).
// ---------------------------------------------------------------------------
__global__ __launch_bounds__(256) void k_final(
        const float* __restrict__ x, const double* __restrict__ S,
        const double* __restrict__ levels, const float* __restrict__ Lp,
        const float* __restrict__ bn1g, const float* __restrict__ bn1b,
        const float* __restrict__ bn2g, const float* __restrict__ bn2b,
        const float* __restrict__ wconv2, float* out) {
    int P = blockIdx.x * 256 + threadIdx.x;
    int b = P >> 14, k = P & (NHW - 1);

    __shared__ float  LpL[640], Ac[NC], Bc[NC], S1[NC];
    __shared__ double levL[NM];
    const float inv = 0.9999950000374997f;
    for (int e = threadIdx.x; e < 640; e += 256) LpL[e] = Lp[b*640 + e];
    if (threadIdx.x < NM) levL[threadIdx.x] = levels[b*NM + threadIdx.x];
    if (threadIdx.x < NC) {
        int c = threadIdx.x;
        Ac[c] = wconv2[c] * (bn2g[c] * inv);       // scales S
        Bc[c] = bn2b[c] + bn1b[c];                 // combined shifts
        S1[c] = bn1g[c] * inv;                     // scales R
    }
    __syncthreads();

    const double* Sb = S + (size_t)b * NHW;
    float v[NM];
#pragma unroll
    for (int i = 0; i < NM; ++i) {
        int j = i * NHW + k;
        int p = j / 10;
        int m = j - p * 10;
        double d = fabs(levL[m] - Sb[p]);
        v[i] = (d < 0.05) ? (float)(1.0 - d) : 0.f;
    }
    float Sk = (float)Sb[k];

    size_t base = (size_t)b * NC * NHW + k;
#pragma unroll 4
    for (int c = 0; c < NC; ++c) {
        float R = 0.f;
#pragma unroll
        for (int i = 0; i < NM; ++i) R = fmaf(LpL[c*10 + i], v[i], R);
        float xcen = out[base + (size_t)c * NHW];      // x_center scratch
        float pre = fmaf(Ac[c], Sk, Bc[c]) + S1[c] * R + xcen;
        float att = 1.0f / (1.0f + expf(-pre));
        out[base + (size_t)c * NHW] = x[base + (size_t)c * NHW] * att;
    }
}

// ---------------------------------------------------------------------------
extern "C" void kernel_launch(void* const* d_in, const int* in_sizes, int n_in,
                              void* d_out, int out_size, void* d_ws, size_t ws_size,
                              hipStream_t stream) {
    (void)in_sizes; (void)n_in; (void)out_size; (void)ws_size;
    const float* x      = (const float*)d_in[0];
    const float* wconv1 = (const float*)d_in[1];
    const float* pw1    = (const float*)d_in[2];
    const float* pw2    = (const float*)d_in[3];
    const float* pw3    = (const float*)d_in[4];
    const float* pw4    = (const float*)d_in[5];
    const float* pgam   = (const float*)d_in[6];
    const float* pbet   = (const float*)d_in[7];
    const float* bn1g   = (const float*)d_in[8];
    const float* bn1b   = (const float*)d_in[9];
    const float* bn2g   = (const float*)d_in[10];
    const float* bn2b   = (const float*)d_in[11];
    const float* fc1w   = (const float*)d_in[12];
    const float* fc1b   = (const float*)d_in[13];
    const float* ph1w   = (const float*)d_in[14];
    const float* ph1b   = (const float*)d_in[15];
    const float* ph2w   = (const float*)d_in[16];
    const float* ph2b   = (const float*)d_in[17];
    const float* ph3w   = (const float*)d_in[18];
    const float* ph3b   = (const float*)d_in[19];
    const float* wconv2 = (const float*)d_in[20];
    float* out = (float*)d_out;

    // workspace layout
    float*  ws  = (float*)d_ws;
    float*  xc  = ws;                                   // 16777216 f32
    double* Sd  = (double*)(ws + 16777216);             // 262144 f64
    double* g   = Sd + NB * NHW;                        // 1024 f64
    double* lev = g + NB * NC;                          // 160 f64
    float*  Lp  = (float*)(lev + NB * NM);              // 10240 f32
    // total ~69.3 MB

    k_gmean<<<NB * NC, 256, 0, stream>>>(x, g);
    k_conv1_S<<<NB * NHW / 256, 256, 0, stream>>>(x, wconv1, g, xc, Sd);
    k_dwchain<<<dim3(16, NC, NB), 256, 0, stream>>>(xc, pw1, pw2, pw3, pw4,
                                                    pgam, pbet, out);
    k_chain<<<NB, 256, 0, stream>>>(Sd, fc1w, fc1b, ph1w, ph1b, ph2w, ph2b,
                                    ph3w, ph3b, lev, Lp);
    k_final<<<NB * NHW / 256, 256, 0, stream>>>(x, Sd, lev, Lp,
                                                bn1g, bn1b, bn2g, bn2b,
                                                wconv2, out);
}

// Round 3
// 199.099 us; speedup vs baseline: 1.1879x; 1.0713x over previous
//
#include <hip/hip_runtime.h>
#include <hip/hip_bf16.h>
#include <math.h>

// Problem constants: B=16, C=OUP=64, H=W=128, HW=16384, M=10
#define NB   16
#define NC   64
#define NH   128
#define NW   128
#define NHW  16384
#define NM   10

// ---------------------------------------------------------------------------
// K0: g[b,c] = mean over HW of x[b,c,:,:]   (f64 accumulation, float4 loads)
// ---------------------------------------------------------------------------
__global__ __launch_bounds__(256) void k_gmean(const float* __restrict__ x,
                                               double* __restrict__ g) {
    int bc = blockIdx.x;                     // 0..1023
    const float* xp = x + (size_t)bc * NHW;
    double s = 0.0;
    for (int i = threadIdx.x; i < NHW / 4; i += 256) {
        float4 v = ((const float4*)xp)[i];
        s += (double)v.x + (double)v.y + (double)v.z + (double)v.w;
    }
    for (int off = 32; off; off >>= 1) s += __shfl_down(s, off);
    __shared__ double red[4];
    int wid = threadIdx.x >> 6, lane = threadIdx.x & 63;
    if (lane == 0) red[wid] = s;
    __syncthreads();
    if (threadIdx.x == 0)
        g[bc] = (red[0] + red[1] + red[2] + red[3]) * (1.0 / (double)NHW);
}

// ---------------------------------------------------------------------------
// K1: x_c = 1x1 conv (W[64,64] @ x) fused with cosine-sim S (f64)
// ---------------------------------------------------------------------------
__global__ __launch_bounds__(256) void k_conv1_S(
        const float* __restrict__ x, const float* __restrict__ W,
        const double* __restrict__ g, float* __restrict__ xc,
        double* __restrict__ S) {
    __shared__ __align__(16) float Xs[64 * 256];  // 64 KB
    __shared__ __align__(16) float Wt[64 * 64];   // 16 KB, Wt[c][o] = W[o][c]
    int bid = blockIdx.x;
    int b = bid >> 6, k0 = (bid & 63) * 256;
    int tid = threadIdx.x;
    const float* xb = x + (size_t)b * NC * NHW + k0;

    for (int e = tid; e < 64 * 64; e += 256) {
        int c = e >> 6, o = e & 63;
        Wt[c * 64 + o] = W[o * 64 + c];
    }
    for (int e = tid; e < 64 * 64; e += 256) {
        int c = e >> 6, p4 = (e & 63) << 2;
        *(float4*)&Xs[c * 256 + p4] =
            *(const float4*)&xb[(size_t)c * NHW + p4];
    }
    __syncthreads();

    // ---- S phase: one pixel per thread, f64 ----
    {
        const double* gb = g + b * NC;
        double num = 0.0, sq = 0.0, gsq = 0.0;
#pragma unroll
        for (int c = 0; c < NC; ++c) {
            double v = (double)Xs[c * 256 + tid];
            double gc = gb[c];
            num += gc * v;
            sq  += v * v;
            gsq += gc * gc;
        }
        double gn = fmax(sqrt(gsq), 1e-8);
        double xn = fmax(sqrt(sq), 1e-8);
        S[(size_t)b * NHW + k0 + tid] = num / (gn * xn);
    }

    // ---- GEMM phase ----
    int pg = tid & 31, og = tid >> 5;
    int px0 = pg * 8, o0 = og * 8;
    float acc[8][8];
#pragma unroll
    for (int i = 0; i < 8; ++i)
#pragma unroll
        for (int j = 0; j < 8; ++j) acc[i][j] = 0.f;

#pragma unroll 4
    for (int c = 0; c < NC; ++c) {
        float4 xa = *(float4*)&Xs[c * 256 + px0];
        float4 xb2 = *(float4*)&Xs[c * 256 + px0 + 4];
        float4 wa = *(float4*)&Wt[c * 64 + o0];
        float4 wb2 = *(float4*)&Wt[c * 64 + o0 + 4];
        float xr[8] = {xa.x, xa.y, xa.z, xa.w, xb2.x, xb2.y, xb2.z, xb2.w};
        float wr[8] = {wa.x, wa.y, wa.z, wa.w, wb2.x, wb2.y, wb2.z, wb2.w};
#pragma unroll
        for (int i = 0; i < 8; ++i)
#pragma unroll
            for (int j = 0; j < 8; ++j)
                acc[i][j] = fmaf(wr[i], xr[j], acc[i][j]);
    }

    float* xcb = xc + (size_t)b * NC * NHW + k0;
#pragma unroll
    for (int i = 0; i < 8; ++i) {
        float4 s0, s1;
        s0.x = acc[i][0]; s0.y = acc[i][1]; s0.z = acc[i][2]; s0.w = acc[i][3];
        s1.x = acc[i][4]; s1.y = acc[i][5]; s1.z = acc[i][6]; s1.w = acc[i][7];
        *(float4*)&xcb[(size_t)(o0 + i) * NHW + px0] = s0;
        *(float4*)&xcb[(size_t)(o0 + i) * NHW + px0 + 4] = s1;
    }
}

// ---------------------------------------------------------------------------
// K2: fused depthwise chain, float4-granular stages (see region map above).
// ---------------------------------------------------------------------------
__global__ __launch_bounds__(256) void k_dwchain(
        const float* __restrict__ xc,
        const float* __restrict__ pw1, const float* __restrict__ pw2,
        const float* __restrict__ pw3, const float* __restrict__ pw4,
        const float* __restrict__ gamma, const float* __restrict__ beta,
        float* __restrict__ outp) {
    int tile = blockIdx.x, c = blockIdx.y, b = blockIdx.z;
    int R0 = (tile >> 2) * 32, C0 = (tile & 3) * 32;
    const float inv = 0.9999950000374997f;   // 1/sqrt(1+1e-5)
    float s0 = gamma[0*NC+c]*inv, b0 = beta[0*NC+c];
    float s1 = gamma[1*NC+c]*inv, b1 = beta[1*NC+c];
    float s2 = gamma[2*NC+c]*inv, b2 = beta[2*NC+c];
    float s3 = gamma[3*NC+c]*inv, b3 = beta[3*NC+c];
    float s4 = gamma[4*NC+c]*inv, b4 = beta[4*NC+c];
    float w1[5], w2[5], w3[5], w4[5];
#pragma unroll
    for (int q = 0; q < 5; ++q) {
        w1[q] = pw1[c*5+q]; w2[q] = pw2[c*5+q];
        w3[q] = pw3[c*5+q]; w4[q] = pw4[c*5+q];
    }
    __shared__ __align__(16) float A[44*44];   // stride 44 (s0), stride 40 (s2)
    __shared__ __align__(16) float Bf[44*40];  // stride 40 (s1), stride 32 (s3)
    const float* src = xc + ((size_t)(b*NC + c)) * NHW;
    int tid = threadIdx.x;

    // stage0: load + bn0 -> A[44][44], zeros outside image
    for (int t = tid; t < 44*11; t += 256) {
        int r = t / 11, g2 = t - r*11;
        int gy = R0 - 6 + r, gx0 = C0 - 6 + 4*g2;
        float4 v = make_float4(0.f, 0.f, 0.f, 0.f);
        bool rowOK = (unsigned)gy < NH;
        if (rowOK) {
            const float* rowp = src + gy*NW;
            if ((unsigned)gx0 <= (unsigned)(NW-4)) {
                v = *(const float4*)(rowp + gx0);
            } else {
                float* pv = (float*)&v;
#pragma unroll
                for (int u = 0; u < 4; ++u) {
                    int gx = gx0 + u;
                    if ((unsigned)gx < NW) pv[u] = rowp[gx];
                }
            }
        }
        float4 w;
        w.x = (rowOK && (unsigned)(gx0+0) < NW) ? fmaf(v.x, s0, b0) : 0.f;
        w.y = (rowOK && (unsigned)(gx0+1) < NW) ? fmaf(v.y, s0, b0) : 0.f;
        w.z = (rowOK && (unsigned)(gx0+2) < NW) ? fmaf(v.z, s0, b0) : 0.f;
        w.w = (rowOK && (unsigned)(gx0+3) < NW) ? fmaf(v.w, s0, b0) : 0.f;
        *(float4*)&A[r*44 + 4*g2] = w;
    }
    __syncthreads();

    // stage1: horizontal 1x5 (+-2) + bn1 -> Bf[44][40]
    for (int t = tid; t < 44*10; t += 256) {
        int r = t / 10, g2 = t - r*10;
        float xw[8];
        *(float4*)&xw[0] = *(float4*)&A[r*44 + 4*g2];
        *(float4*)&xw[4] = *(float4*)&A[r*44 + 4*g2 + 4];
        int gy = R0 - 6 + r;
        bool rowOK = (unsigned)gy < NH;
        float o[4];
#pragma unroll
        for (int u = 0; u < 4; ++u) {
            float acc = 0.f;
#pragma unroll
            for (int q = 0; q < 5; ++q) acc = fmaf(w1[q], xw[u+q], acc);
            int gx = C0 - 4 + 4*g2 + u;
            o[u] = (rowOK && (unsigned)gx < NW) ? fmaf(acc, s1, b1) : 0.f;
        }
        *(float4*)&Bf[r*40 + 4*g2] = *(float4*)o;
    }
    __syncthreads();

    // stage2: vertical 5x1 (+-2) + bn2 -> A[40][40]
    // (reads Bf only, writes A only -> no intra-stage barrier needed)
    for (int t = tid; t < 40*10; t += 256) {
        int r = t / 10, g2 = t - r*10;
        float ys[5][4];
#pragma unroll
        for (int p = 0; p < 5; ++p)
            *(float4*)&ys[p][0] = *(float4*)&Bf[(r+p)*40 + 4*g2];
        int gy = R0 - 4 + r;
        bool rowOK = (unsigned)gy < NH;
        float o[4];
#pragma unroll
        for (int u = 0; u < 4; ++u) {
            float acc = 0.f;
#pragma unroll
            for (int p = 0; p < 5; ++p) acc = fmaf(w2[p], ys[p][u], acc);
            int gx = C0 - 4 + 4*g2 + u;
            o[u] = (rowOK && (unsigned)gx < NW) ? fmaf(acc, s2, b2) : 0.f;
        }
        *(float4*)&A[r*40 + 4*g2] = *(float4*)o;
    }
    __syncthreads();

    // stage3: horizontal 1x5 dil2 (+-4) + bn3 -> Bf[40][32]
    for (int t = tid; t < 40*8; t += 256) {
        int r = t >> 3, g2 = t & 7;
        float xw[12];
        *(float4*)&xw[0] = *(float4*)&A[r*40 + 4*g2];
        *(float4*)&xw[4] = *(float4*)&A[r*40 + 4*g2 + 4];
        *(float4*)&xw[8] = *(float4*)&A[r*40 + 4*g2 + 8];
        int gy = R0 - 4 + r;
        bool rowOK = (unsigned)gy < NH;
        float o[4];
#pragma unroll
        for (int u = 0; u < 4; ++u) {
            float acc = 0.f;
#pragma unroll
            for (int q = 0; q < 5; ++q) acc = fmaf(w3[q], xw[u+2*q], acc);
            o[u] = rowOK ? fmaf(acc, s3, b3) : 0.f;
        }
        *(float4*)&Bf[r*32 + 4*g2] = *(float4*)o;
    }
    __syncthreads();

    // stage4: vertical 5x1 dil2 (+-4) + bn4 -> global (d_out scratch)
    {
        int r = tid >> 3, g2 = tid & 7;
        float ys[5][4];
#pragma unroll
        for (int p = 0; p < 5; ++p)
            *(float4*)&ys[p][0] = *(float4*)&Bf[(r+2*p)*32 + 4*g2];
        float o[4];
#pragma unroll
        for (int u = 0; u < 4; ++u) {
            float acc = 0.f;
#pragma unroll
            for (int p = 0; p < 5; ++p) acc = fmaf(w4[p], ys[p][u], acc);
            o[u] = fmaf(acc, s4, b4);
        }
        float* dst = outp + ((size_t)(b*NC + c)) * NHW;
        *(float4*)&dst[(R0+r)*NW + C0 + 4*g2] = *(float4*)o;
    }
}

// ---------------------------------------------------------------------------
// K3: per-batch chain (min/max, histogram, fc, phi, softmax, Lp)
// ---------------------------------------------------------------------------
__global__ __launch_bounds__(256) void k_chain(
        const double* __restrict__ S,
        const float* __restrict__ fc1w, const float* __restrict__ fc1b,
        const float* __restrict__ ph1w, const float* __restrict__ ph1b,
        const float* __restrict__ ph2w, const float* __restrict__ ph2b,
        const float* __restrict__ ph3w, const float* __restrict__ ph3b,
        double* __restrict__ levelsOut, float* __restrict__ LpOut) {
    int b = blockIdx.x, tid = threadIdx.x;
    const double* Sb = S + b * NHW;

    double mn = 1e300, mx = -1e300;
    for (int i = tid; i < NHW; i += 256) {
        double v = Sb[i];
        mn = fmin(mn, v); mx = fmax(mx, v);
    }
    for (int off = 32; off; off >>= 1) {
        mn = fmin(mn, __shfl_down(mn, off));
        mx = fmax(mx, __shfl_down(mx, off));
    }
    __shared__ double rmn[4], rmx[4];
    int wid = tid >> 6, lane = tid & 63;
    if (lane == 0) { rmn[wid] = mn; rmx[wid] = mx; }
    __syncthreads();
    __shared__ double levS[NM];
    if (tid == 0) {
        double a = fmin(fmin(rmn[0], rmn[1]), fmin(rmn[2], rmn[3]));
        double z = fmax(fmax(rmx[0], rmx[1]), fmax(rmx[2], rmx[3]));
        for (int m = 0; m < NM; ++m) levS[m] = a + (z - a) * ((double)m / 9.0);
    }
    __syncthreads();
    double lv[NM];
#pragma unroll
    for (int m = 0; m < NM; ++m) lv[m] = levS[m];

    double bins[NM];
#pragma unroll
    for (int m = 0; m < NM; ++m) bins[m] = 0.0;
    for (int i = tid; i < NHW; i += 256) {
        double v = Sb[i];
#pragma unroll
        for (int m = 0; m < NM; ++m) {
            double d = fabs(lv[m] - v);
            if (d < 0.05) bins[m] += 1.0 - d;
        }
    }
#pragma unroll
    for (int m = 0; m < NM; ++m)
        for (int off = 32; off; off >>= 1) bins[m] += __shfl_down(bins[m], off);
    __shared__ double wb[4][NM];
    if (lane == 0) {
#pragma unroll
        for (int m = 0; m < NM; ++m) wb[wid][m] = bins[m];
    }
    __syncthreads();
    __shared__ float ratio[NM];
    if (tid == 0) {
        double den = 0.0;
        for (int m = 0; m < NM; ++m) {
            double cs = wb[0][m] + wb[1][m] + wb[2][m] + wb[3][m];
            den += cs;
            ratio[m] = (float)(cs / den);
        }
    }
    __syncthreads();

    __shared__ float CfL[640];
    for (int idx = tid; idx < 640; idx += 256) {
        int rm = idx >> 6, o = idx & 63;
        CfL[idx] = ratio[rm] * fc1w[o*2+0] + (float)levS[rm] * fc1w[o*2+1] + fc1b[o];
    }
    __syncthreads();

    __shared__ float P1[640], P2[640], P3[640];
    for (int idx = tid; idx < 640; idx += 256) {
        int o = idx / 10, m = idx - o * 10;
        float a1 = ph1b[o], a2 = ph2b[o], a3 = ph3b[o];
        for (int c2 = 0; c2 < NC; ++c2) {
            float cq = CfL[c2*10 + m];
            a1 = fmaf(ph1w[o*NC + c2], cq, a1);
            a2 = fmaf(ph2w[o*NC + c2], cq, a2);
            a3 = fmaf(ph3w[o*NC + c2], cq, a3);
        }
        P1[idx] = a1; P2[idx] = a2; P3[idx] = a3;
    }
    __syncthreads();

    __shared__ float XL[100];
    if (tid < 100) {
        int m = tid / 10, n = tid - (tid/10)*10;
        float acc = 0.f;
        for (int c2 = 0; c2 < NC; ++c2)
            acc = fmaf(P1[c2*10 + m], P2[c2*10 + n], acc);
        XL[tid] = acc;
    }
    __syncthreads();
    if (tid < NM) {
        float mxr = XL[tid*10];
        for (int n = 1; n < NM; ++n) mxr = fmaxf(mxr, XL[tid*10 + n]);
        float e[NM], sum = 0.f;
        for (int n = 0; n < NM; ++n) { e[n] = expf(XL[tid*10+n] - mxr); sum += e[n]; }
        for (int n = 0; n < NM; ++n) XL[tid*10+n] = e[n] / sum;
    }
    __syncthreads();

    for (int idx = tid; idx < 640; idx += 256) {
        int c2 = idx / 10, n = idx - (idx/10)*10;
        float acc = 0.f;
#pragma unroll
        for (int m = 0; m < NM; ++m) acc = fmaf(P3[c2*10 + m], XL[m*10 + n], acc);
        LpOut[b*640 + idx] = acc;
    }
    if (tid < NM) levelsOut[b*NM + tid] = levS[tid];
}

// ---------------------------------------------------------------------------
// K4: final fusion.
// ---------------------------------------------------------------------------
__global__ __launch_bounds__(256) void k_final(
        const float* __restrict__ x, const double* __restrict__ S,
        const double* __restrict__ levels, const float* __restrict__ Lp,
        const float* __restrict__ bn1g, const float* __restrict__ bn1b,
        const float* __restrict__ bn2g, const float* __restrict__ bn2b,
        const float* __restrict__ wconv2, float* out) {
    int P = blockIdx.x * 256 + threadIdx.x;
    int b = P >> 14, k = P & (NHW - 1);

    __shared__ float  LpL[640], Ac[NC], Bc[NC], S1[NC];
    __shared__ double levL[NM];
    const float inv = 0.9999950000374997f;
    for (int e = threadIdx.x; e < 640; e += 256) LpL[e] = Lp[b*640 + e];
    if (threadIdx.x < NM) levL[threadIdx.x] = levels[b*NM + threadIdx.x];
    if (threadIdx.x < NC) {
        int c = threadIdx.x;
        Ac[c] = wconv2[c] * (bn2g[c] * inv);
        Bc[c] = bn2b[c] + bn1b[c];
        S1[c] = bn1g[c] * inv;
    }
    __syncthreads();

    const double* Sb = S + (size_t)b * NHW;
    float v[NM];
#pragma unroll
    for (int i = 0; i < NM; ++i) {
        int j = i * NHW + k;
        int p = j / 10;
        int m = j - p * 10;
        double d = fabs(levL[m] - Sb[p]);
        v[i] = (d < 0.05) ? (float)(1.0 - d) : 0.f;
    }
    float Sk = (float)Sb[k];

    size_t base = (size_t)b * NC * NHW + k;
#pragma unroll 4
    for (int c = 0; c < NC; ++c) {
        float R = 0.f;
#pragma unroll
        for (int i = 0; i < NM; ++i) R = fmaf(LpL[c*10 + i], v[i], R);
        float xcen = out[base + (size_t)c * NHW];
        float pre = fmaf(Ac[c], Sk, Bc[c]) + S1[c] * R + xcen;
        float att = 1.0f / (1.0f + expf(-pre));
        out[base + (size_t)c * NHW] = x[base + (size_t)c * NHW] * att;
    }
}

// ---------------------------------------------------------------------------
extern "C" void kernel_launch(void* const* d_in, const int* in_sizes, int n_in,
                              void* d_out, int out_size, void* d_ws, size_t ws_size,
                              hipStream_t stream) {
    (void)in_sizes; (void)n_in; (void)out_size; (void)ws_size;
    const float* x      = (const float*)d_in[0];
    const float* wconv1 = (const float*)d_in[1];
    const float* pw1    = (const float*)d_in[2];
    const float* pw2    = (const float*)d_in[3];
    const float* pw3    = (const float*)d_in[4];
    const float* pw4    = (const float*)d_in[5];
    const float* pgam   = (const float*)d_in[6];
    const float* pbet   = (const float*)d_in[7];
    const float* bn1g   = (const float*)d_in[8];
    const float* bn1b   = (const float*)d_in[9];
    const float* bn2g   = (const float*)d_in[10];
    const float* bn2b   = (const float*)d_in[11];
    const float* fc1w   = (const float*)d_in[12];
    const float* fc1b   = (const float*)d_in[13];
    const float* ph1w   = (const float*)d_in[14];
    const float* ph1b   = (const float*)d_in[15];
    const float* ph2w   = (const float*)d_in[16];
    const float* ph2b   = (const float*)d_in[17];
    const float* ph3w   = (const float*)d_in[18];
    const float* ph3b   = (const float*)d_in[19];
    const float* wconv2 = (const float*)d_in[20];
    float* out = (float*)d_out;

    float*  ws  = (float*)d_ws;
    float*  xc  = ws;                                   // 16777216 f32
    double* Sd  = (double*)(ws + 16777216);             // 262144 f64
    double* g   = Sd + NB * NHW;                        // 1024 f64
    double* lev = g + NB * NC;                          // 160 f64
    float*  Lp  = (float*)(lev + NB * NM);              // 10240 f32

    k_gmean<<<NB * NC, 256, 0, stream>>>(x, g);
    k_conv1_S<<<NB * NHW / 256, 256, 0, stream>>>(x, wconv1, g, xc, Sd);
    k_dwchain<<<dim3(16, NC, NB), 256, 0, stream>>>(xc, pw1, pw2, pw3, pw4,
                                                    pgam, pbet, out);
    k_chain<<<NB, 256, 0, stream>>>(Sd, fc1w, fc1b, ph1w, ph1b, ph2w, ph2b,
                                    ph3w, ph3b, lev, Lp);
    k_final<<<NB * NHW / 256, 256, 0, stream>>>(x, Sd, lev, Lp,
                                                bn1g, bn1b, bn2g, bn2b,
                                                wconv2, out);
}